// Round 6
// baseline (3679.477 us; speedup 1.0000x reference)
//
#include <hip/hip_runtime.h>
#include <cmath>

// DHT: out[n,c,a,r] = sum over px (x,y) of feat[n,c,y,x],
//   r = rint((x-128)*cos(a deg) + (y-128)*sin(a deg)) + 361   (always in [180,542])
// feat[4,128,256,256] f32 -> out[4,128,180,723] f32.
//
// Locked-in findings:
//  R1-R4 (~31ms): LDS ds_add_f32 serializes ~per-lane (~200cyc/wave-op) ->
//    NEVER use LDS f32 atomics on the hot path.
//  R5 (2.69ms): wave-private rows + stride-4 lane columns + plain program-
//    ordered DS RMW works. New costs: 8-way bank conflicts (stride-4 ->
//    SQ_LDS_BANK_CONFLICT 2.3e8), divergent run-merge (saves no wave-ops),
//    1 block/CU, px spill under 64-VGPR bound.
//  R6: +swizzle addr=b+(b>>5) (row pad 384), branchless sign-templated walk,
//    512-thr blocks x (image,phase) grid -> 32 waves/CU, 32-reg px tile.

#define NA 180
#define NR 723
#define HW 65536
#define NC 512
#define CH 2            // angles per chunk
#define ROW_W 368       // valid swizzled span: bins rl in [4,366] -> swz <= 377
#define ROW_PAD 384     // allocated row width (multiple of 32)
#define RBASE 176
#define NWIN 32         // 8-px windows along the scan axis

__device__ __forceinline__ bool is_phase2(int a) { return a >= 46 && a <= 134; }

// ---------------------------------------------------------------------------
// Kernel A (validated R4/R5, unchanged): win[a][w][fast] u32 =
// base bin r at scan=8w (bits 0..15), step bits 16..22 (scan 8w+1..8w+7).
// Phase-1 rows (a in [0,45]u[135,179]): fast=x, scan=y (coef sin(a) >= 0).
// Phase-2 rows (a in [46,134]):         fast=y, scan=x (coef cos(a), sign flips at 90).
// fp64 non-fused mul/add + rint bit-matches np.round.
// ---------------------------------------------------------------------------
__global__ __launch_bounds__(256) void dht_win(unsigned int* __restrict__ win) {
    const int lane = threadIdx.x;
    const int w = blockIdx.x;
    const int a = blockIdx.y;
    const double theta = (double)a * (M_PI / 180.0);
    const double c = cos(theta), s = sin(theta);
    const bool p2 = is_phase2(a);
    int prev = 0;
    unsigned int word = 0;
    #pragma unroll
    for (int i = 0; i < 8; ++i) {
        const int k = w * 8 + i;
        const int x = p2 ? k : lane;
        const int y = p2 ? lane : k;
        const double rho = __dadd_rn(__dmul_rn((double)(x - 128), c),
                                     __dmul_rn((double)(y - 128), s));
        int r = (int)rint(rho) + 361;
        r = min(max(r, 0), NR - 1);
        if (i == 0) word = (unsigned int)r;
        else if (r != prev) word |= (1u << (15 + i));
        prev = r;
    }
    win[((size_t)a * NWIN + w) * 256 + lane] = word;
}

// Branchless 8(scan) x 4(col) walk. SGN is the wave-uniform step sign.
// Concurrent lanes are 4 columns apart -> bins >= 2.83 apart -> distinct
// addresses (race-free with program-ordered same-wave DS ops).
// Swizzle: word addr = bin + (bin>>5)  (+1 pad per 32 words -> stride-4 lane
// groups land on disjoint bank sets; ~2-way residue instead of 8-way).
template <int SGN>
__device__ __forceinline__ void walk8x4(const uint4 wq, const float (&px)[8][4],
                                        float* __restrict__ rp) {
    #pragma unroll
    for (int j = 0; j < 4; ++j) {
        const unsigned int wrd = (&wq.x)[j];
        int bin = (int)(wrd & 0xffffu) - RBASE;
        #pragma unroll
        for (int k = 0; k < 8; ++k) {
            if (k) bin += SGN * (int)((wrd >> (15 + k)) & 1u);
            rp[bin + (bin >> 5)] += px[k][j];
        }
    }
}

// ---------------------------------------------------------------------------
// Kernel B: block = 512 thr = 8 waves, one (image, phase). Wave wv owns scan
// windows w=4wv..4wv+3 (scan 32wv..32wv+31); lane owns 4 fast-axis columns
// 4l..4l+3. Private rows[wave][CH][ROW_PAD]; flush sums the 8 wave copies.
// ---------------------------------------------------------------------------
__global__ __launch_bounds__(512, 8) void dht_main(const float* __restrict__ feat,
                                                   const unsigned int* __restrict__ win,
                                                   float* __restrict__ out) {
    __shared__ float rows[8 * CH * ROW_PAD];   // 24.6 KB
    const int t = threadIdx.x;
    const int wv = t >> 6;
    const int l = t & 63;
    const int nc = blockIdx.x;
    const int phase = blockIdx.y;
    const int nAng = phase ? 89 : 91;
    const float* __restrict__ fbase = feat + (size_t)nc * HW;
    float* __restrict__ obase = out + (size_t)nc * (NA * NR);

    for (int cb = 0; cb < nAng; cb += CH) {
        const int cn = min(CH, nAng - cb);
        for (int i = t; i < 8 * CH * ROW_PAD; i += 512) rows[i] = 0.f;
        __syncthreads();

        #pragma unroll
        for (int w2 = 0; w2 < 4; ++w2) {
            const int w = 4 * wv + w2;
            const int k0 = 8 * w;             // scan offset of this window
            float px[8][4];
            if (phase == 0) {
                // scan=y: rows y=k0+k, cols x=4l..4l+3 -> coalesced float4
                #pragma unroll
                for (int k = 0; k < 8; ++k) {
                    const float4 q = *(const float4*)(fbase + ((k0 + k) << 8) + 4 * l);
                    px[k][0] = q.x; px[k][1] = q.y; px[k][2] = q.z; px[k][3] = q.w;
                }
            } else {
                // scan=x: rows y=4l+j, cols x=k0..k0+7 -> 2 float4 per row
                #pragma unroll
                for (int j = 0; j < 4; ++j) {
                    const float4 q0 = *(const float4*)(fbase + ((4 * l + j) << 8) + k0);
                    const float4 q1 = *(const float4*)(fbase + ((4 * l + j) << 8) + k0 + 4);
                    px[0][j] = q0.x; px[1][j] = q0.y; px[2][j] = q0.z; px[3][j] = q0.w;
                    px[4][j] = q1.x; px[5][j] = q1.y; px[6][j] = q1.z; px[7][j] = q1.w;
                }
            }

            for (int ai = 0; ai < cn; ++ai) {
                const int aidx = cb + ai;
                const int a = phase ? (46 + aidx) : (aidx <= 45 ? aidx : aidx + 89);
                const uint4 wq = *(const uint4*)(win + ((size_t)a * NWIN + w) * 256 + 4 * l);
                float* __restrict__ rp = rows + (wv * CH + ai) * ROW_PAD;
                if (phase && a > 90) walk8x4<-1>(wq, px, rp);
                else                 walk8x4<+1>(wq, px, rp);
            }
        }
        __syncthreads();

        // flush: sum 8 wave copies (swizzled read), write all 723 bins
        for (int i = t; i < cn * NR; i += 512) {
            const int al = i / NR;
            const int r = i - al * NR;
            const int aidx = cb + al;
            const int a = phase ? (46 + aidx) : (aidx <= 45 ? aidx : aidx + 89);
            float sum = 0.f;
            const int rl = r - RBASE;
            if (rl >= 0 && rl < ROW_W) {
                const int ad = rl + (rl >> 5);
                #pragma unroll
                for (int wv2 = 0; wv2 < 8; ++wv2)
                    sum += rows[(wv2 * CH + al) * ROW_PAD + ad];
            }
            obase[(size_t)a * NR + r] = sum;
        }
        __syncthreads();
    }
}

extern "C" void kernel_launch(void* const* d_in, const int* in_sizes, int n_in,
                              void* d_out, int out_size, void* d_ws, size_t ws_size,
                              hipStream_t stream) {
    const float* feat = (const float*)d_in[0];
    float* out = (float*)d_out;
    unsigned int* win = (unsigned int*)d_ws;

    const size_t win_bytes = (size_t)NA * NWIN * 256 * sizeof(unsigned int); // 5.9MB
    if (ws_size < win_bytes) return;

    hipLaunchKernelGGL(dht_win, dim3(NWIN, NA), dim3(256), 0, stream, win);
    hipLaunchKernelGGL(dht_main, dim3(NC, 2), dim3(512), 0, stream, feat, win, out);
}

// Round 7
// 1808.253 us; speedup vs baseline: 2.0348x; 2.0348x over previous
//
#include <hip/hip_runtime.h>
#include <cmath>

// DHT: out[n,c,a,r] = sum over px (x,y) of feat[n,c,y,x],
//   r = rint((x-128)*cos(a deg) + (y-128)*sin(a deg)) + 361  (r in [180,542])
// feat[4,128,256,256] f32 -> out[4,128,180,723] f32.
//
// Locked-in findings:
//  R1-R4 (~31ms): LDS f32 atomicAdd serializes ~per-lane -> never on hot path.
//  R5 (2.69ms): wave-private rows + 4-col lane stride + plain program-ordered
//    DS RMW works (race-free: lane bin spacing 4|coef|>=2.83 -> distinct).
//  R6 (3.88ms): chunked image re-reads went to HBM at >1 block/CU (FETCH
//    1.6->10.9GB); bin+(bin>>5) swizzle INCREASED conflicts. Both reverted.
//  R7: px REGISTER-PERSISTENT across all angles (zero re-reads) via
//    (image-pair, phase, scan-half) blocks; float2 rows = 2 images per DS
//    RMW (half the wave-ops); scan-halves merged by exactly-2 commutative
//    global atomic adds (deterministic); out pre-zeroed each launch.

#define NA 180
#define NR 723
#define HW 65536
#define NC 512
#define CH 2            // angles per LDS chunk
#define ROW_W 368       // bins rl = r-RBASE in [4,366]
#define ROW_PAD 384
#define RBASE 176
#define NWIN 32         // 8-px windows along the scan axis

__device__ __forceinline__ bool is_phase2(int a) { return a >= 46 && a <= 134; }

// ---------------------------------------------------------------------------
// win[a][w][fast] u32 = base bin at scan=8w (bits 0..15), step bits 16..22.
// Phase-1 (a in [0,45]u[135,179]): fast=x, scan=y (step coef sin(a)>=0).
// Phase-2 (a in [46,134]):         fast=y, scan=x (step coef cos(a), sign
// flips at a=90). fp64 non-fused mul/add + rint bit-matches np.round
// (validated R1-R6: absmax 0.25 = f32 sum-order noise only).
// ---------------------------------------------------------------------------
__global__ __launch_bounds__(256) void dht_win(unsigned int* __restrict__ win) {
    const int lane = threadIdx.x;
    const int w = blockIdx.x;
    const int a = blockIdx.y;
    const double theta = (double)a * (M_PI / 180.0);
    const double c = cos(theta), s = sin(theta);
    const bool p2 = is_phase2(a);
    int prev = 0;
    unsigned int word = 0;
    #pragma unroll
    for (int i = 0; i < 8; ++i) {
        const int k = w * 8 + i;
        const int x = p2 ? k : lane;
        const int y = p2 ? lane : k;
        const double rho = __dadd_rn(__dmul_rn((double)(x - 128), c),
                                     __dmul_rn((double)(y - 128), s));
        int r = (int)rint(rho) + 361;
        r = min(max(r, 0), NR - 1);
        if (i == 0) word = (unsigned int)r;
        else if (r != prev) word |= (1u << (15 + i));
        prev = r;
    }
    win[((size_t)a * NWIN + w) * 256 + lane] = word;
}

__global__ __launch_bounds__(256) void zero_out(float4* __restrict__ o, int n4) {
    const int i = blockIdx.x * 256 + threadIdx.x;
    if (i < n4) o[i] = make_float4(0.f, 0.f, 0.f, 0.f);
}

// Branchless 8(scan) x 4(col) x 2(img) walk; concurrent lanes 4 columns
// apart -> bins >= 2 apart -> distinct b64 addresses (race-free, program-
// ordered same-wave DS). No swizzle (R6 evidence).
template <int SGN>
__device__ __forceinline__ void walk2(const uint4 wq, const float2 (&px)[8][4],
                                      float2* __restrict__ rp) {
    #pragma unroll
    for (int j = 0; j < 4; ++j) {
        const unsigned int wrd = (&wq.x)[j];
        int bin = (int)(wrd & 0xffffu) - RBASE;
        #pragma unroll
        for (int k = 0; k < 8; ++k) {
            if (k) bin += SGN * (int)((wrd >> (15 + k)) & 1u);
            float2 v = rp[bin];
            v.x += px[k][j].x;
            v.y += px[k][j].y;
            rp[bin] = v;
        }
    }
}

// ---------------------------------------------------------------------------
// Block = (image-pair, phase, scan-half). 1024 thr = 16 waves; wave wv owns
// scan window w = 16h+wv (8 scan lines); lane owns 4 fast columns 4l..4l+3.
// px float2[8][4] (64 VGPR) loaded ONCE, reused across all angles of the
// phase. rows[16 waves][CH][ROW_PAD] float2 = 96 KB -> 1 block/CU.
// ---------------------------------------------------------------------------
__global__ __launch_bounds__(1024, 4) void dht_main(const float* __restrict__ feat,
                                                    const unsigned int* __restrict__ win,
                                                    float* __restrict__ out) {
    __shared__ float2 rows[16 * CH * ROW_PAD];   // 96 KB
    const int t = threadIdx.x;
    const int wv = t >> 6;
    const int l = t & 63;
    const int pair = blockIdx.x;
    const int phase = blockIdx.y;
    const int h = blockIdx.z;
    const int w = 16 * h + wv;          // scan window 0..31
    const int k0 = 8 * w;               // scan offset
    const float* __restrict__ f0 = feat + (size_t)(2 * pair) * HW;
    const float* __restrict__ f1 = feat + (size_t)(2 * pair + 1) * HW;
    float* __restrict__ o0 = out + (size_t)(2 * pair) * (NA * NR);
    float* __restrict__ o1 = out + (size_t)(2 * pair + 1) * (NA * NR);

    // ---- load persistent px tile: 8 scan x 4 col x 2 img ----
    float2 px[8][4];
    if (phase == 0) {
        // scan=y: rows y=k0+k, cols x=4l..4l+3 (fully coalesced float4)
        #pragma unroll
        for (int k = 0; k < 8; ++k) {
            const float4 a0 = *(const float4*)(f0 + ((k0 + k) << 8) + 4 * l);
            const float4 a1 = *(const float4*)(f1 + ((k0 + k) << 8) + 4 * l);
            px[k][0] = make_float2(a0.x, a1.x); px[k][1] = make_float2(a0.y, a1.y);
            px[k][2] = make_float2(a0.z, a1.z); px[k][3] = make_float2(a0.w, a1.w);
        }
    } else {
        // scan=x: rows y=4l+j, cols x=k0..k0+7 (2 aligned float4 per row/img)
        #pragma unroll
        for (int j = 0; j < 4; ++j) {
            const float4 b0 = *(const float4*)(f0 + ((4 * l + j) << 8) + k0);
            const float4 b1 = *(const float4*)(f0 + ((4 * l + j) << 8) + k0 + 4);
            const float4 c0 = *(const float4*)(f1 + ((4 * l + j) << 8) + k0);
            const float4 c1 = *(const float4*)(f1 + ((4 * l + j) << 8) + k0 + 4);
            px[0][j] = make_float2(b0.x, c0.x); px[1][j] = make_float2(b0.y, c0.y);
            px[2][j] = make_float2(b0.z, c0.z); px[3][j] = make_float2(b0.w, c0.w);
            px[4][j] = make_float2(b1.x, c1.x); px[5][j] = make_float2(b1.y, c1.y);
            px[6][j] = make_float2(b1.z, c1.z); px[7][j] = make_float2(b1.w, c1.w);
        }
    }

    const int nAng = phase ? 89 : 91;
    for (int cb = 0; cb < nAng; cb += CH) {
        const int cn = min(CH, nAng - cb);
        for (int i = t; i < 16 * CH * ROW_PAD; i += 1024)
            rows[i] = make_float2(0.f, 0.f);
        __syncthreads();

        for (int ai = 0; ai < cn; ++ai) {
            const int aidx = cb + ai;
            const int a = phase ? (46 + aidx) : (aidx <= 45 ? aidx : aidx + 89);
            const uint4 wq = *(const uint4*)(win + ((size_t)a * NWIN + w) * 256 + 4 * l);
            float2* __restrict__ rp = rows + (wv * CH + ai) * ROW_PAD;
            if (phase && a > 90) walk2<-1>(wq, px, rp);
            else                 walk2<+1>(wq, px, rp);
        }
        __syncthreads();

        // flush: sum the 16 wave copies; exactly-2 atomic contributions per
        // out element (the two scan-halves) -> commutative -> deterministic.
        for (int i = t; i < cn * ROW_W; i += 1024) {
            const int al = i / ROW_W;
            const int rl = i - al * ROW_W;
            float sx = 0.f, sy = 0.f;
            #pragma unroll
            for (int c2 = 0; c2 < 16; ++c2) {
                const float2 v = rows[(c2 * CH + al) * ROW_PAD + rl];
                sx += v.x; sy += v.y;
            }
            const int aidx = cb + al;
            const int a = phase ? (46 + aidx) : (aidx <= 45 ? aidx : aidx + 89);
            const size_t o = (size_t)a * NR + (RBASE + rl);
            unsafeAtomicAdd(o0 + o, sx);
            unsafeAtomicAdd(o1 + o, sy);
        }
        __syncthreads();
    }
}

extern "C" void kernel_launch(void* const* d_in, const int* in_sizes, int n_in,
                              void* d_out, int out_size, void* d_ws, size_t ws_size,
                              hipStream_t stream) {
    const float* feat = (const float*)d_in[0];
    float* out = (float*)d_out;
    unsigned int* win = (unsigned int*)d_ws;

    const size_t win_bytes = (size_t)NA * NWIN * 256 * sizeof(unsigned int); // 5.9MB
    if (ws_size < win_bytes) return;

    const int n4 = out_size / 4;   // out_size = 512*180*723, divisible by 4
    hipLaunchKernelGGL(zero_out, dim3((n4 + 255) / 256), dim3(256), 0, stream,
                       (float4*)out, n4);
    hipLaunchKernelGGL(dht_win, dim3(NWIN, NA), dim3(256), 0, stream, win);
    hipLaunchKernelGGL(dht_main, dim3(NC / 2, 2, 2), dim3(1024), 0, stream,
                       feat, win, out);
}

// Round 8
// 1606.365 us; speedup vs baseline: 2.2906x; 1.1257x over previous
//
#include <hip/hip_runtime.h>
#include <cmath>

// DHT: out[n,c,a,r] = sum over px (x,y) of feat[n,c,y,x],
//   r = rint((x-128)*cos(a deg) + (y-128)*sin(a deg)) + 361  (r in [180,542])
// feat[4,128,256,256] f32 -> out[4,128,180,723] f32.
//
// Locked-in findings:
//  R1-R4 (~31ms): LDS f32 atomicAdd serializes ~per-lane -> never on hot path.
//  R5 (2.69ms): wave-private rows + 4-col lane stride + plain program-ordered
//    DS RMW (race-free: lane bin spacing 4|coef|>=2.83 -> distinct bins).
//  R6 (3.88ms): >1 block/CU with chunked re-reads -> HBM-bound; additive
//    swizzle b+(b>>5) made conflicts worse.
//  R7 (1.85ms): register-persistent px across ALL angles (FETCH 0.6GB);
//    cycle model closes: 2.4M cyc DS-issue + 1.76M cyc bank conflicts.
//  R8: kill the conflicts. Bijective quarter-split swizzle
//    e(b) = (b>>2) + (b&3)*96  (quarter offset 192 words == 0 mod 32):
//    within each quarter lanes sit at word-stride 2|coef| in [1.41,2] ->
//    near-uniform banks at EVERY angle (the frozen low-2-bits of b, which
//    defeated any high-bit swizzle, become the quarter selector).
//    Bijective -> race-freedom identical to R7. +3 VALU/RMW (hidden, DS-bound).

#define NA 180
#define NR 723
#define HW 65536
#define NC 512
#define CH 2            // angles per LDS chunk
#define ROW_W 368       // bins rl = r-RBASE in [4,366]
#define ROW_PAD 384     // 4 quarters x 96
#define QW 96           // quarter width (192 words == 0 mod 32 -> bank-neutral)
#define RBASE 176
#define NWIN 32         // 8-px windows along the scan axis

__device__ __forceinline__ bool is_phase2(int a) { return a >= 46 && a <= 134; }

// swizzled element index inside a 384-element row (bijective on [0,384))
__device__ __forceinline__ int swz(int b) { return (b >> 2) + (b & 3) * QW; }

// ---------------------------------------------------------------------------
// win[a][w][fast] u32 = base bin at scan=8w (bits 0..15), step bits 16..22.
// Phase-1 (a in [0,45]u[135,179]): fast=x, scan=y (step coef sin(a)>=0).
// Phase-2 (a in [46,134]):         fast=y, scan=x (step coef cos(a), sign
// flips at a=90). fp64 non-fused mul/add + rint bit-matches np.round
// (validated R1-R7: absmax 0.25 = f32 sum-order noise only).
// ---------------------------------------------------------------------------
__global__ __launch_bounds__(256) void dht_win(unsigned int* __restrict__ win) {
    const int lane = threadIdx.x;
    const int w = blockIdx.x;
    const int a = blockIdx.y;
    const double theta = (double)a * (M_PI / 180.0);
    const double c = cos(theta), s = sin(theta);
    const bool p2 = is_phase2(a);
    int prev = 0;
    unsigned int word = 0;
    #pragma unroll
    for (int i = 0; i < 8; ++i) {
        const int k = w * 8 + i;
        const int x = p2 ? k : lane;
        const int y = p2 ? lane : k;
        const double rho = __dadd_rn(__dmul_rn((double)(x - 128), c),
                                     __dmul_rn((double)(y - 128), s));
        int r = (int)rint(rho) + 361;
        r = min(max(r, 0), NR - 1);
        if (i == 0) word = (unsigned int)r;
        else if (r != prev) word |= (1u << (15 + i));
        prev = r;
    }
    win[((size_t)a * NWIN + w) * 256 + lane] = word;
}

__global__ __launch_bounds__(256) void zero_out(float4* __restrict__ o, int n4) {
    const int i = blockIdx.x * 256 + threadIdx.x;
    if (i < n4) o[i] = make_float4(0.f, 0.f, 0.f, 0.f);
}

// Branchless 8(scan) x 4(col) x 2(img) walk; concurrent lanes 4 columns
// apart -> bins >= 2.83 apart -> distinct (bijective swizzle preserves it).
template <int SGN>
__device__ __forceinline__ void walk2(const uint4 wq, const float2 (&px)[8][4],
                                      float2* __restrict__ rp) {
    #pragma unroll
    for (int j = 0; j < 4; ++j) {
        const unsigned int wrd = (&wq.x)[j];
        int bin = (int)(wrd & 0xffffu) - RBASE;
        #pragma unroll
        for (int k = 0; k < 8; ++k) {
            if (k) bin += SGN * (int)((wrd >> (15 + k)) & 1u);
            const int e = swz(bin);
            float2 v = rp[e];
            v.x += px[k][j].x;
            v.y += px[k][j].y;
            rp[e] = v;
        }
    }
}

// ---------------------------------------------------------------------------
// Block = (image-pair, phase, scan-half). 1024 thr = 16 waves; wave wv owns
// scan window w = 16h+wv (8 scan lines); lane owns 4 fast columns 4l..4l+3.
// px float2[8][4] loaded ONCE, reused across all angles of the phase.
// rows[16 waves][CH][ROW_PAD] float2 = 96 KB -> 1 block/CU.
// ---------------------------------------------------------------------------
__global__ __launch_bounds__(1024, 4) void dht_main(const float* __restrict__ feat,
                                                    const unsigned int* __restrict__ win,
                                                    float* __restrict__ out) {
    __shared__ float2 rows[16 * CH * ROW_PAD];   // 96 KB
    const int t = threadIdx.x;
    const int wv = t >> 6;
    const int l = t & 63;
    const int pair = blockIdx.x;
    const int phase = blockIdx.y;
    const int h = blockIdx.z;
    const int w = 16 * h + wv;          // scan window 0..31
    const int k0 = 8 * w;               // scan offset
    const float* __restrict__ f0 = feat + (size_t)(2 * pair) * HW;
    const float* __restrict__ f1 = feat + (size_t)(2 * pair + 1) * HW;
    float* __restrict__ o0 = out + (size_t)(2 * pair) * (NA * NR);
    float* __restrict__ o1 = out + (size_t)(2 * pair + 1) * (NA * NR);

    // ---- load persistent px tile: 8 scan x 4 col x 2 img ----
    float2 px[8][4];
    if (phase == 0) {
        // scan=y: rows y=k0+k, cols x=4l..4l+3 (fully coalesced float4)
        #pragma unroll
        for (int k = 0; k < 8; ++k) {
            const float4 a0 = *(const float4*)(f0 + ((k0 + k) << 8) + 4 * l);
            const float4 a1 = *(const float4*)(f1 + ((k0 + k) << 8) + 4 * l);
            px[k][0] = make_float2(a0.x, a1.x); px[k][1] = make_float2(a0.y, a1.y);
            px[k][2] = make_float2(a0.z, a1.z); px[k][3] = make_float2(a0.w, a1.w);
        }
    } else {
        // scan=x: rows y=4l+j, cols x=k0..k0+7 (2 aligned float4 per row/img)
        #pragma unroll
        for (int j = 0; j < 4; ++j) {
            const float4 b0 = *(const float4*)(f0 + ((4 * l + j) << 8) + k0);
            const float4 b1 = *(const float4*)(f0 + ((4 * l + j) << 8) + k0 + 4);
            const float4 c0 = *(const float4*)(f1 + ((4 * l + j) << 8) + k0);
            const float4 c1 = *(const float4*)(f1 + ((4 * l + j) << 8) + k0 + 4);
            px[0][j] = make_float2(b0.x, c0.x); px[1][j] = make_float2(b0.y, c0.y);
            px[2][j] = make_float2(b0.z, c0.z); px[3][j] = make_float2(b0.w, c0.w);
            px[4][j] = make_float2(b1.x, c1.x); px[5][j] = make_float2(b1.y, c1.y);
            px[6][j] = make_float2(b1.z, c1.z); px[7][j] = make_float2(b1.w, c1.w);
        }
    }

    const int nAng = phase ? 89 : 91;
    for (int cb = 0; cb < nAng; cb += CH) {
        const int cn = min(CH, nAng - cb);
        for (int i = t; i < 16 * CH * ROW_PAD; i += 1024)
            rows[i] = make_float2(0.f, 0.f);
        __syncthreads();

        for (int ai = 0; ai < cn; ++ai) {
            const int aidx = cb + ai;
            const int a = phase ? (46 + aidx) : (aidx <= 45 ? aidx : aidx + 89);
            const uint4 wq = *(const uint4*)(win + ((size_t)a * NWIN + w) * 256 + 4 * l);
            float2* __restrict__ rp = rows + (wv * CH + ai) * ROW_PAD;
            if (phase && a > 90) walk2<-1>(wq, px, rp);
            else                 walk2<+1>(wq, px, rp);
        }
        __syncthreads();

        // flush: sum the 16 wave copies (swizzled read); exactly-2 atomic
        // contributions per out element (the two scan-halves) -> deterministic.
        for (int i = t; i < cn * ROW_W; i += 1024) {
            const int al = i / ROW_W;
            const int rl = i - al * ROW_W;
            const int ad = swz(rl);
            float sx = 0.f, sy = 0.f;
            #pragma unroll
            for (int c2 = 0; c2 < 16; ++c2) {
                const float2 v = rows[(c2 * CH + al) * ROW_PAD + ad];
                sx += v.x; sy += v.y;
            }
            const int aidx = cb + al;
            const int a = phase ? (46 + aidx) : (aidx <= 45 ? aidx : aidx + 89);
            const size_t o = (size_t)a * NR + (RBASE + rl);
            unsafeAtomicAdd(o0 + o, sx);
            unsafeAtomicAdd(o1 + o, sy);
        }
        __syncthreads();
    }
}

extern "C" void kernel_launch(void* const* d_in, const int* in_sizes, int n_in,
                              void* d_out, int out_size, void* d_ws, size_t ws_size,
                              hipStream_t stream) {
    const float* feat = (const float*)d_in[0];
    float* out = (float*)d_out;
    unsigned int* win = (unsigned int*)d_ws;

    const size_t win_bytes = (size_t)NA * NWIN * 256 * sizeof(unsigned int); // 5.9MB
    if (ws_size < win_bytes) return;

    const int n4 = out_size / 4;   // out_size = 512*180*723, divisible by 4
    hipLaunchKernelGGL(zero_out, dim3((n4 + 255) / 256), dim3(256), 0, stream,
                       (float4*)out, n4);
    hipLaunchKernelGGL(dht_win, dim3(NWIN, NA), dim3(256), 0, stream, win);
    hipLaunchKernelGGL(dht_main, dim3(NC / 2, 2, 2), dim3(1024), 0, stream,
                       feat, win, out);
}